// Round 4
// baseline (389.480 us; speedup 1.0000x reference)
//
#include <hip/hip_runtime.h>
#include <hip/hip_cooperative_groups.h>
#include <math.h>

namespace cg = cooperative_groups;

#define BB 16
#define CC 256
#define HH 128
#define WW 128
#define HWSZ (HH * WW)   // 16384

typedef float floatx4 __attribute__((ext_vector_type(4)));

// ---------------------------------------------------------------------------
// One cooperative kernel, three phases separated by grid.sync():
//   1) channel avg/max pool (x read #1, caching loads -> x tail stays in L3)
//   2) 7x7 conv over [avg;max] + sigmoid -> M  (2 MB in, 1 MB out, L2-bound)
//   3) out = x * M  (x read #2 served mostly by L3; NT loads/stores so the
//      out stream does not evict x)
// All phases are grid-stride so any grid <= co-resident capacity is correct.
// ---------------------------------------------------------------------------
__global__ __launch_bounds__(256) void fused_kernel(
    const float* __restrict__ x, const float* __restrict__ wgt,
    float* __restrict__ out, float* __restrict__ avg_p,
    float* __restrict__ max_p, float* __restrict__ Mbuf)
{
    cg::grid_group grid = cg::this_grid();
    const int nblk = gridDim.x;
    const int nthr = nblk << 8;           // nblk * 256

    __shared__ float4 sS[8][32];
    __shared__ float4 sM[8][32];
    __shared__ float  sw[98];

    // stage conv weights once (constant input, safe before phase 2)
    if (threadIdx.x < 98) sw[threadIdx.x] = wgt[threadIdx.x];
    __syncthreads();

    // ---------------- phase 1: pool ----------------
    {
        const int tf4   = threadIdx.x & 31;   // f4 group within tile
        const int split = threadIdx.x >> 5;   // 0..7 channel split
        const int c0    = split * 32;

        for (int tile = blockIdx.x; tile < 2048; tile += nblk) {
            const int p0 = tile * 128;                 // first pixel of tile
            const int b  = p0 >> 14;                   // p0 / HWSZ
            const int hw = (p0 & (HWSZ - 1)) + tf4 * 4;
            const float* xb = x + (size_t)b * CC * HWSZ + hw;

            float4 s = make_float4(0.f, 0.f, 0.f, 0.f);
            float4 m = make_float4(-INFINITY, -INFINITY, -INFINITY, -INFINITY);
            #pragma unroll 8
            for (int i = 0; i < 32; ++i) {
                float4 v = *(const float4*)(xb + (size_t)(c0 + i) * HWSZ);
                s.x += v.x; s.y += v.y; s.z += v.z; s.w += v.w;
                m.x = fmaxf(m.x, v.x); m.y = fmaxf(m.y, v.y);
                m.z = fmaxf(m.z, v.z); m.w = fmaxf(m.w, v.w);
            }
            sS[split][tf4] = s;
            sM[split][tf4] = m;
            __syncthreads();

            for (int off = 4; off >= 1; off >>= 1) {
                if (split < off) {
                    float4 a  = sS[split][tf4], b2 = sS[split + off][tf4];
                    a.x += b2.x; a.y += b2.y; a.z += b2.z; a.w += b2.w;
                    sS[split][tf4] = a;
                    float4 ma = sM[split][tf4], mb = sM[split + off][tf4];
                    ma.x = fmaxf(ma.x, mb.x); ma.y = fmaxf(ma.y, mb.y);
                    ma.z = fmaxf(ma.z, mb.z); ma.w = fmaxf(ma.w, mb.w);
                    sM[split][tf4] = ma;
                }
                __syncthreads();
            }

            if (split == 0) {
                float4 a = sS[0][tf4];
                const float inv = 1.0f / CC;
                a.x *= inv; a.y *= inv; a.z *= inv; a.w *= inv;
                *(float4*)(avg_p + (size_t)b * HWSZ + hw) = a;
                *(float4*)(max_p + (size_t)b * HWSZ + hw) = sM[0][tf4];
            }
            __syncthreads();   // protect sS/sM before next tile iteration
        }
    }

    __threadfence();
    grid.sync();

    // ---------------- phase 2: conv + sigmoid ----------------
    {
        for (int idx = (blockIdx.x << 8) + threadIdx.x; idx < BB * HWSZ; idx += nthr) {
            const int b  = idx >> 14;
            const int hw = idx & (HWSZ - 1);
            const int h  = hw >> 7;
            const int w  = hw & 127;

            const float* ap = avg_p + (size_t)b * HWSZ;
            const float* mp = max_p + (size_t)b * HWSZ;

            float acc = 0.f;
            #pragma unroll
            for (int kh = 0; kh < 7; ++kh) {
                const int hh = h + kh - 3;
                if (hh < 0 || hh >= HH) continue;
                #pragma unroll
                for (int kw = 0; kw < 7; ++kw) {
                    const int ww2 = w + kw - 3;
                    if (ww2 < 0 || ww2 >= WW) continue;
                    const int off = hh * WW + ww2;
                    acc += ap[off] * sw[kh * 7 + kw];
                    acc += mp[off] * sw[49 + kh * 7 + kw];
                }
            }
            Mbuf[idx] = 1.0f / (1.0f + expf(-acc));
        }
    }

    __threadfence();
    grid.sync();

    // ---------------- phase 3: out = x * M ----------------
    {
        const int n4 = BB * CC * HWSZ / 4;   // 16,777,216
        const floatx4* xv4 = (const floatx4*)x;
        floatx4*       ov4 = (floatx4*)out;

        for (int i = (blockIdx.x << 8) + threadIdx.x; i < n4; i += nthr) {
            const int b   = i >> 20;         // CC*HWSZ/4 = 2^20
            const int hw4 = i & 4095;        // HWSZ/4 = 4096
            floatx4 xv = __builtin_nontemporal_load(xv4 + i);
            floatx4 mv = *(const floatx4*)(Mbuf + ((size_t)b << 14) + (hw4 << 2));
            __builtin_nontemporal_store(xv * mv, ov4 + i);
        }
    }
}

extern "C" void kernel_launch(void* const* d_in, const int* in_sizes, int n_in,
                              void* d_out, int out_size, void* d_ws, size_t ws_size,
                              hipStream_t stream) {
    const float* x   = (const float*)d_in[0];
    const float* wgt = (const float*)d_in[1];
    float* out = (float*)d_out;

    float* avg_p = (float*)d_ws;
    float* max_p = avg_p + (size_t)BB * HWSZ;
    float* Mbuf  = max_p + (size_t)BB * HWSZ;

    // clamp grid to guaranteed co-residency for the cooperative launch
    int maxPerCU = 0;
    hipOccupancyMaxActiveBlocksPerMultiprocessor(&maxPerCU, (const void*)fused_kernel, 256, 0);
    if (maxPerCU < 1) maxPerCU = 1;
    int grid = maxPerCU * 256;      // 256 CUs on MI355X
    if (grid > 2048) grid = 2048;

    void* args[] = {(void*)&x, (void*)&wgt, (void*)&out,
                    (void*)&avg_p, (void*)&max_p, (void*)&Mbuf};
    hipLaunchCooperativeKernel((void*)fused_kernel, dim3(grid), dim3(256),
                               args, 0, stream);
}

// Round 5
// 145.087 us; speedup vs baseline: 2.6845x; 2.6845x over previous
//
#include <hip/hip_runtime.h>
#include <math.h>

#define BB 16
#define CC 256
#define HH 128
#define WW 128
#define HWSZ (HH * WW)   // 16384

typedef float floatx4 __attribute__((ext_vector_type(4)));

// ---------------------------------------------------------------------------
// Kernel 1: channel-wise avg & max pool.
// Tile = 256 pixels. Block = 256 threads = 64 f4-lanes x 4 channel-splits.
// Every wave load instruction covers 1 KB contiguous (64 lanes x 16 B).
// Each thread reduces 64 channels (stride HWSZ floats = 64 KB).
// Caching loads ON PURPOSE: x must stay resident in L3 for kernel 2's reread.
// ---------------------------------------------------------------------------
__global__ __launch_bounds__(256) void pool_kernel(const float* __restrict__ x,
                                                   float* __restrict__ avg_out,
                                                   float* __restrict__ max_out) {
    const int tf4   = threadIdx.x & 63;   // f4 group within 256-px tile
    const int split = threadIdx.x >> 6;   // 0..3 channel split
    const int p0    = blockIdx.x * 256;   // first pixel of tile
    const int b     = p0 >> 14;           // p0 / HWSZ (tiles never straddle b)
    const int hw    = (p0 & (HWSZ - 1)) + tf4 * 4;

    const float* xb = x + (size_t)b * CC * HWSZ + hw;

    float4 s = make_float4(0.f, 0.f, 0.f, 0.f);
    float4 m = make_float4(-INFINITY, -INFINITY, -INFINITY, -INFINITY);

    const int c0 = split * 64;
    #pragma unroll 8
    for (int i = 0; i < 64; ++i) {
        float4 v = *(const float4*)(xb + (size_t)(c0 + i) * HWSZ);
        s.x += v.x; s.y += v.y; s.z += v.z; s.w += v.w;
        m.x = fmaxf(m.x, v.x); m.y = fmaxf(m.y, v.y);
        m.z = fmaxf(m.z, v.z); m.w = fmaxf(m.w, v.w);
    }

    __shared__ float4 sS[4][64];
    __shared__ float4 sM[4][64];
    sS[split][tf4] = s;
    sM[split][tf4] = m;
    __syncthreads();

    for (int off = 2; off >= 1; off >>= 1) {
        if (split < off) {
            float4 a  = sS[split][tf4], b2 = sS[split + off][tf4];
            a.x += b2.x; a.y += b2.y; a.z += b2.z; a.w += b2.w;
            sS[split][tf4] = a;
            float4 ma = sM[split][tf4], mb = sM[split + off][tf4];
            ma.x = fmaxf(ma.x, mb.x); ma.y = fmaxf(ma.y, mb.y);
            ma.z = fmaxf(ma.z, mb.z); ma.w = fmaxf(ma.w, mb.w);
            sM[split][tf4] = ma;
        }
        __syncthreads();
    }

    if (split == 0) {
        float4 a = sS[0][tf4];
        const float inv = 1.0f / CC;
        a.x *= inv; a.y *= inv; a.z *= inv; a.w *= inv;
        *(float4*)(avg_out + (size_t)b * HWSZ + hw) = a;
        *(float4*)(max_out + (size_t)b * HWSZ + hw) = sM[0][tf4];
    }
}

// ---------------------------------------------------------------------------
// Kernel 2: conv(7x7)+sigmoid fused with the broadcast multiply.
// Block = one 2-row strip (256 px) of one batch image.
//   phase a: 1 px/thread conv over [avg;max] (L2-resident, 2 MB) -> M in LDS
//   phase b: 64 channel-iterations; wave w handles channel 4c+w; every load
//            is 1 KB contiguous per wave. M sits in one register (f4/thread).
// x loads + out stores are NONTEMPORAL: x's last use (don't re-allocate),
// and the out stream must not evict the x tail other blocks still need.
// ---------------------------------------------------------------------------
__global__ __launch_bounds__(256) void convmul_kernel(const float* __restrict__ x,
                                                      const float* __restrict__ avg_p,
                                                      const float* __restrict__ max_p,
                                                      const float* __restrict__ wgt,
                                                      float* __restrict__ out) {
    __shared__ float sw[98];
    __shared__ float sMl[256];

    const int tid = threadIdx.x;
    if (tid < 98) sw[tid] = wgt[tid];
    __syncthreads();

    const int strip = blockIdx.x;        // 0..1023
    const int b     = strip >> 6;        // 64 strips per batch
    const int h0    = (strip & 63) * 2;  // first of the strip's 2 rows

    // ---- phase a: conv + sigmoid for this strip's 256 pixels ----
    {
        const int hl = tid >> 7;          // 0/1 row within strip
        const int w  = tid & 127;
        const int h  = h0 + hl;
        const float* ap = avg_p + (size_t)b * HWSZ;
        const float* mp = max_p + (size_t)b * HWSZ;

        float acc = 0.f;
        #pragma unroll
        for (int kh = 0; kh < 7; ++kh) {
            const int hh = h + kh - 3;
            if (hh < 0 || hh >= HH) continue;
            #pragma unroll
            for (int kw = 0; kw < 7; ++kw) {
                const int ww2 = w + kw - 3;
                if (ww2 < 0 || ww2 >= WW) continue;
                const int off = hh * WW + ww2;
                acc += ap[off] * sw[kh * 7 + kw];
                acc += mp[off] * sw[49 + kh * 7 + kw];
            }
        }
        sMl[tid] = 1.0f / (1.0f + expf(-acc));
    }
    __syncthreads();

    // ---- phase b: out = x * M over all 256 channels ----
    const int g    = tid & 63;            // f4 group within strip (64 x 4 px)
    const int csub = tid >> 6;            // wave id 0..3
    const floatx4 mv = ((const floatx4*)sMl)[g];

    const size_t base = (size_t)b * CC * HWSZ + (size_t)h0 * WW + (size_t)g * 4;
    const float* xp = x + base;
    float*       op = out + base;

    #pragma unroll 4
    for (int c = 0; c < 64; ++c) {
        const size_t coff = (size_t)(c * 4 + csub) * HWSZ;
        floatx4 xv = __builtin_nontemporal_load((const floatx4*)(xp + coff));
        __builtin_nontemporal_store(xv * mv, (floatx4*)(op + coff));
    }
}

extern "C" void kernel_launch(void* const* d_in, const int* in_sizes, int n_in,
                              void* d_out, int out_size, void* d_ws, size_t ws_size,
                              hipStream_t stream) {
    const float* x   = (const float*)d_in[0];
    const float* wgt = (const float*)d_in[1];
    float* out = (float*)d_out;

    float* avg_p = (float*)d_ws;                   // 1 MB
    float* max_p = avg_p + (size_t)BB * HWSZ;      // 1 MB

    // 1) channel pool: 1024 tiles of 256 px
    pool_kernel<<<1024, 256, 0, stream>>>(x, avg_p, max_p);

    // 2) conv+sigmoid+multiply: 1024 strips of 2 rows
    convmul_kernel<<<1024, 256, 0, stream>>>(x, avg_p, max_p, wgt, out);
}